// Round 10
// baseline (51.157 us; speedup 1.0000x reference)
//
#include <hip/hip_runtime.h>

#define TBL_BITS 17
#define TBL_SIZE (1u << TBL_BITS)
#define TBL_MASK (TBL_SIZE - 1u)

#define GBLK 768           // k_a grid: 196608 threads (exactly the work size)
#define BLK  256

// RESHAPE SEMANTICS: edge_proj.reshape(H,E) on a row-major [E,4] buffer is
// axis-scrambled: edge_proj[h,e] = flat[h*65536+e]. Softmax group h = flat
// range [h*65536,(h+1)*65536). Always index flat buffers directly.
// Same for node_proj[h,d,f] = npflat[h*262144 + d*64 + f].
//
// NOTE (R6): cooperative grid.sync() costs ~230 us on this 8-XCD chip. Plain
// dispatch boundaries (~1.5 us) are strictly better.
// NOTE (R7): native f32 atomics (unsafeAtomicAdd) + probe ILP: -7.4 us.
// NOTE (R9): single-pass dedup (atomicMax claim; winner adds ep[e]-ep[old]
// so the superseded contribution cancels): 3 -> 2 dispatches, -6.0 us.
// NOTE (R10): balanced k_a block roles, 1 MB table, shfl stats reduce.

struct Args {
    const float* X;  const float* Xe;
    const int* src;  const int* dst;
    const float* Wn; const float* bn;
    const float* We; const float* be;
    float* out;
    float* nproj;        // [4096*256] flat
    float* ep;           // [65536*4] flat, PRE-EXPONENTIATED matrix elements
    float* partials;     // [1024] per-wave scalar exp-sums (group h = idx>>8)
    unsigned long long* tbl;  // [TBL_SIZE] dedup hash (1 MB)
};

__device__ __forceinline__ unsigned hash_key(unsigned key) {
    return (key * 2654435761u) >> (32 - TBL_BITS);
}

// ---------------------------------------------------------------------------
// K_A (768 blocks, balanced roles):
//   blocks [0,256):   zero d_out       + node GEMM (first half)
//   blocks [256,512): zero hash table  + node GEMM (second half)
//   blocks [512,768): edge GEMM -> exp + per-wave flat-order sums
// Node GEMM: 8 rows/thread (Wn element reused 512x). Edge GEMM: no max-sub
// (|logit*0.25| <= ~1.3; softmax shift-invariant, denom rel-err ~1e-7).
// ---------------------------------------------------------------------------
__global__ __launch_bounds__(BLK, 4) void k_a(Args A) {
    const int tid = blockIdx.x * BLK + threadIdx.x;
    {   // zero d_out (65536 f4) + hash table (65536 f4)
        const float4 z = make_float4(0.f, 0.f, 0.f, 0.f);
        if (tid < 65536)       ((float4*)A.out)[tid] = z;
        else if (tid < 131072) ((float4*)A.tbl)[tid - 65536] = z;
    }
    if (tid < 131072) {  // node GEMM: col c, rows g+512r (r=0..7)
        const int c = tid & 255;
        const int g = tid >> 8;  // 0..511, block-uniform
        const float b = A.bn[c];
        float acc[8];
#pragma unroll
        for (int r = 0; r < 8; ++r) acc[r] = b;
        const float* Wc = A.Wn + c;
#pragma unroll 8
        for (int k = 0; k < 64; ++k) {
            const float w = Wc[k * 256];
#pragma unroll
            for (int r = 0; r < 8; ++r)
                acc[r] = fmaf(A.X[(g + 512 * r) * 64 + k], w, acc[r]);
        }
#pragma unroll
        for (int r = 0; r < 8; ++r)
            A.nproj[(g + 512 * r) * 256 + c] = acc[r];
    } else {  // tid in [131072, 196608): edge GEMM row e + exp + wave sums
        const int e = tid - 131072;
        const float4* xi = (const float4*)(A.Xe + (size_t)e * 16);
        float x[16];
        float4 v;
        v = xi[0]; x[0]=v.x;  x[1]=v.y;  x[2]=v.z;  x[3]=v.w;
        v = xi[1]; x[4]=v.x;  x[5]=v.y;  x[6]=v.z;  x[7]=v.w;
        v = xi[2]; x[8]=v.x;  x[9]=v.y;  x[10]=v.z; x[11]=v.w;
        v = xi[3]; x[12]=v.x; x[13]=v.y; x[14]=v.z; x[15]=v.w;
        float a0 = A.be[0], a1 = A.be[1], a2 = A.be[2], a3 = A.be[3];
#pragma unroll
        for (int k = 0; k < 16; ++k) {
            a0 = fmaf(x[k], A.We[k * 4 + 0], a0);
            a1 = fmaf(x[k], A.We[k * 4 + 1], a1);
            a2 = fmaf(x[k], A.We[k * 4 + 2], a2);
            a3 = fmaf(x[k], A.We[k * 4 + 3], a3);
        }
        const float e0 = expf(a0 * 0.25f), e1 = expf(a1 * 0.25f);
        const float e2 = expf(a2 * 0.25f), e3 = expf(a3 * 0.25f);
        ((float4*)A.ep)[e] = make_float4(e0, e1, e2, e3);
        // Edge-wave (e>>6) covers ep flat [256(e>>6), +256): one head group.
        float s = e0 + e1 + e2 + e3;
#pragma unroll
        for (int off = 32; off > 0; off >>= 1) s += __shfl_xor(s, off);
        if ((e & 63) == 0) A.partials[e >> 6] = s;
    }
}

// ---------------------------------------------------------------------------
// K_B (2048 blocks): claims + stats + message, one pass.
//   1) lanes 0..7 each run the claim/max loop for edge w*8+lane (8 atomic
//      chains in parallel per wave); winner may carry sub_e (superseded edge).
//   2) stats: thread t loads partials4[t] (head = t>>6 = wave id), 6-step
//      shfl_xor reduce, lane 0 writes s_stats[head]; one barrier.
//   3) per-edge: winner adds sum_h (ep[h,e]-ep[h,sub_e])*r_h*nproj[h,d,:] --
//      the superseded duplicate's contribution cancels exactly (~1e-10).
// ---------------------------------------------------------------------------
__global__ __launch_bounds__(BLK, 4) void k_b(Args A) {
    const int tid  = blockIdx.x * BLK + threadIdx.x;
    const int w    = tid >> 6;   // 0..8191
    const int lane = tid & 63;   // = feature f

    // 1) claims (lanes 0..7; e = w*8 + lane)
    int action = 0, sub_e = -1, sv = 0, dv = 0;
    if (lane < 8) {
        const int e = w * 8 + lane;
        sv = A.src[e];
        dv = A.dst[e];
        const unsigned key = ((unsigned)sv << 12) | (unsigned)dv;
        const unsigned long long tag  = (unsigned long long)(key + 1u);
        const unsigned long long pack = (tag << 24) | (unsigned long long)e;
        unsigned idx = hash_key(key);
        while (true) {
            unsigned long long cur = A.tbl[idx];
            if (cur == 0ull) {
                unsigned long long old = atomicCAS(&A.tbl[idx], 0ull, pack);
                if (old == 0ull) { action = 1; break; }  // claimed empty slot
                cur = old;
            }
            if ((cur >> 24) == tag) {
                const unsigned long long old = atomicMax(&A.tbl[idx], pack);
                if (old < pack) {            // we are the new winner
                    action = 1;
                    sub_e = (int)(old & 0xFFFFFFull);
                }                            // else: bigger e already added
                break;
            }
            idx = (idx + 1u) & TBL_MASK;
        }
    }

    // 2) stats: r_h = 0.25 / sum(partials[256h .. 256h+256))
    __shared__ float s_stats[4];
    {
        const int t = threadIdx.x;
        const float4 p = ((const float4*)A.partials)[t];  // head = t>>6
        float s = p.x + p.y + p.z + p.w;
#pragma unroll
        for (int off = 32; off > 0; off >>= 1) s += __shfl_xor(s, off);
        if ((t & 63) == 0) s_stats[t >> 6] = 0.25f / s;
        __syncthreads();
    }
    const float r0 = s_stats[0], r1 = s_stats[1];
    const float r2 = s_stats[2], r3 = s_stats[3];

    // 3) process the wave's 8 edges
#pragma unroll
    for (int j = 0; j < 8; ++j) {
        const int act = __shfl(action, j);
        if (!act) continue;
        const int e  = w * 8 + j;
        const int sj = __shfl(sv, j);
        const int dj = __shfl(dv, j);
        const int se = __shfl(sub_e, j);
        float c0 = A.ep[e];
        float c1 = A.ep[65536 + e];
        float c2 = A.ep[131072 + e];
        float c3 = A.ep[196608 + e];
        if (se >= 0) {                      // cancel superseded duplicate
            c0 -= A.ep[se];
            c1 -= A.ep[65536 + se];
            c2 -= A.ep[131072 + se];
            c3 -= A.ep[196608 + se];
        }
        const int base = dj * 64 + lane;
        float v = c0 * r0 * A.nproj[base];
        v = fmaf(c1 * r1, A.nproj[base + 262144], v);
        v = fmaf(c2 * r2, A.nproj[base + 524288], v);
        v = fmaf(c3 * r3, A.nproj[base + 786432], v);
        unsafeAtomicAdd(&A.out[sj * 64 + lane], v);
    }
}

// ---------------------------------------------------------------------------
extern "C" void kernel_launch(void* const* d_in, const int* in_sizes, int n_in,
                              void* d_out, int out_size, void* d_ws, size_t ws_size,
                              hipStream_t stream) {
    Args A;
    A.X   = (const float*)d_in[0];
    A.Xe  = (const float*)d_in[1];
    A.src = (const int*)d_in[2];
    A.dst = (const int*)d_in[3];
    A.Wn  = (const float*)d_in[4];
    A.bn  = (const float*)d_in[5];
    A.We  = (const float*)d_in[6];
    A.be  = (const float*)d_in[7];
    A.out = (float*)d_out;
    char* ws   = (char*)d_ws;
    A.nproj    = (float*)ws;                                     // 4 MB
    A.ep       = (float*)(ws + 4u * 1024u * 1024u);              // 1 MB
    A.partials = (float*)(ws + 5u * 1024u * 1024u);              // 4 KB
    A.tbl      = (unsigned long long*)(ws + 6u * 1024u * 1024u); // 1 MB

    k_a<<<GBLK, BLK, 0, stream>>>(A);
    k_b<<<2048, BLK, 0, stream>>>(A);
}

// Round 11
// 46.277 us; speedup vs baseline: 1.1054x; 1.1054x over previous
//
#include <hip/hip_runtime.h>

#define TBL_BITS 18
#define TBL_SIZE (1u << TBL_BITS)
#define TBL_MASK (TBL_SIZE - 1u)

#define GBLK 1024          // k_a grid: 262144 threads
#define BLK  256

// RESHAPE SEMANTICS: edge_proj.reshape(H,E) on a row-major [E,4] buffer is
// axis-scrambled: edge_proj[h,e] = flat[h*65536+e]. Softmax group h = flat
// range [h*65536,(h+1)*65536). Always index flat buffers directly.
// Same for node_proj[h,d,f] = npflat[h*262144 + d*64 + f].
//
// NOTE (R6): cooperative grid.sync() costs ~230 us on this 8-XCD chip. Plain
// dispatch boundaries (~1.5 us) are strictly better.
// NOTE (R7): native f32 atomics (unsafeAtomicAdd) + probe ILP: -7.4 us.
// NOTE (R9): single-pass dedup: atomicMax claims winner; new winner adds
// (ep[e]-ep[old])*r_h so the superseded contribution cancels. 3 -> 2 dispatches.
// NOTE (R10): role-balanced k_a + 1MB table + 8-wide claims REGRESSED
// (46.6 -> 51.2 us); exact R9 config re-landed. This is the empirical floor:
// harness per-iteration 256 MiB ws-fill = ~42 us at 80% HBM peak (in-stream,
// serialized, untouchable) + ~4.5 us roofline-justified kernel work.

struct Args {
    const float* X;  const float* Xe;
    const int* src;  const int* dst;
    const float* Wn; const float* bn;
    const float* We; const float* be;
    float* out;
    float* nproj;        // [4096*256] flat
    float* ep;           // [65536*4] flat, PRE-EXPONENTIATED matrix elements
    float* partials;     // [1024] per-wave scalar exp-sums (wave w -> group w>>8)
    unsigned long long* tbl;  // [TBL_SIZE] dedup hash
};

__device__ __forceinline__ unsigned hash_key(unsigned key) {
    return (key * 2654435761u) >> (32 - TBL_BITS);
}

// ---------------------------------------------------------------------------
// K_A: zero out+tbl; node GEMM (8 rows/thread, Wn element read 512x);
//      edge GEMM -> exp (no max-sub: |logit*0.25| <= ~1.3, shift-invariant)
//      + per-wave scalar sums in FLAT order (group h = wave>>8).
// ---------------------------------------------------------------------------
__global__ __launch_bounds__(BLK, 4) void k_a(Args A) {
    const int tid = blockIdx.x * BLK + threadIdx.x;
    {   // zero d_out (65536 f4) + hash table (131072 f4)
        const float4 z = make_float4(0.f, 0.f, 0.f, 0.f);
        if (tid < 65536)       ((float4*)A.out)[tid] = z;
        else if (tid < 196608) ((float4*)A.tbl)[tid - 65536] = z;
    }
    if (tid < 131072) {  // node GEMM: col c, rows g+512r (r=0..7)
        const int c = tid & 255;
        const int g = tid >> 8;  // 0..511, block-uniform
        const float b = A.bn[c];
        float acc[8];
#pragma unroll
        for (int r = 0; r < 8; ++r) acc[r] = b;
        const float* Wc = A.Wn + c;
#pragma unroll 8
        for (int k = 0; k < 64; ++k) {
            const float w = Wc[k * 256];
#pragma unroll
            for (int r = 0; r < 8; ++r)
                acc[r] = fmaf(A.X[(g + 512 * r) * 64 + k], w, acc[r]);
        }
#pragma unroll
        for (int r = 0; r < 8; ++r)
            A.nproj[(g + 512 * r) * 256 + c] = acc[r];
    }
    if (tid < 65536) {  // edge GEMM row `tid` + exp + per-wave flat-order sum
        const float4* xi = (const float4*)(A.Xe + (size_t)tid * 16);
        float x[16];
        float4 v;
        v = xi[0]; x[0]=v.x;  x[1]=v.y;  x[2]=v.z;  x[3]=v.w;
        v = xi[1]; x[4]=v.x;  x[5]=v.y;  x[6]=v.z;  x[7]=v.w;
        v = xi[2]; x[8]=v.x;  x[9]=v.y;  x[10]=v.z; x[11]=v.w;
        v = xi[3]; x[12]=v.x; x[13]=v.y; x[14]=v.z; x[15]=v.w;
        float a0 = A.be[0], a1 = A.be[1], a2 = A.be[2], a3 = A.be[3];
#pragma unroll
        for (int k = 0; k < 16; ++k) {
            a0 = fmaf(x[k], A.We[k * 4 + 0], a0);
            a1 = fmaf(x[k], A.We[k * 4 + 1], a1);
            a2 = fmaf(x[k], A.We[k * 4 + 2], a2);
            a3 = fmaf(x[k], A.We[k * 4 + 3], a3);
        }
        const float e0 = expf(a0 * 0.25f), e1 = expf(a1 * 0.25f);
        const float e2 = expf(a2 * 0.25f), e3 = expf(a3 * 0.25f);
        ((float4*)A.ep)[tid] = make_float4(e0, e1, e2, e3);
        // Wave w covers flat [256w, 256w+256), inside group h = w>>8.
        float s = e0 + e1 + e2 + e3;
#pragma unroll
        for (int off = 32; off > 0; off >>= 1) s += __shfl_xor(s, off);
        if ((tid & 63) == 0) A.partials[tid >> 6] = s;
    }
}

// ---------------------------------------------------------------------------
// K_B (2048 blocks): per-block stats reduce + single-pass dedup + message.
// Wave per 8 edges (lane = feature). For each 4-edge batch, lanes 0..3 run
// the claim/max loop (4 atomic chains overlap); decisions broadcast by shfl.
// Winner adds Σ_h (ep[h,e] - ep[h,old_e]) * r_h * nproj[h,d,:] so a
// superseded duplicate's contribution cancels exactly (|err| ~1e-10).
// ---------------------------------------------------------------------------
__global__ __launch_bounds__(BLK, 4) void k_b(Args A) {
    __shared__ float4 red[256];
    __shared__ float s_stats[4];
    {   // stats: r_h = 0.25 / sum(partials[256h .. 256h+256))
        const int t = threadIdx.x;
        red[t] = make_float4(A.partials[t], A.partials[256 + t],
                             A.partials[512 + t], A.partials[768 + t]);
        __syncthreads();
        for (int s = 128; s > 0; s >>= 1) {
            if (t < s) {
                red[t].x += red[t + s].x; red[t].y += red[t + s].y;
                red[t].z += red[t + s].z; red[t].w += red[t + s].w;
            }
            __syncthreads();
        }
        if (t == 0) {
            s_stats[0] = 0.25f / red[0].x;
            s_stats[1] = 0.25f / red[0].y;
            s_stats[2] = 0.25f / red[0].z;
            s_stats[3] = 0.25f / red[0].w;
        }
        __syncthreads();
    }
    const float r0 = s_stats[0], r1 = s_stats[1];
    const float r2 = s_stats[2], r3 = s_stats[3];

    const int tid  = blockIdx.x * BLK + threadIdx.x;
    const int w    = tid >> 6;   // 0..8191
    const int lane = tid & 63;   // = feature f

#pragma unroll
    for (int i = 0; i < 8; i += 4) {
        const int ebase = w * 8 + i;
        // lanes 0..3: resolve table for edge ebase+lane.
        // action: 0 = loser/skip, 1 = add (sub_e<0: plain add; else subtract old)
        int action = 0;
        int sub_e  = -1;
        if (lane < 4) {
            const int e = ebase + lane;
            const unsigned key = ((unsigned)A.src[e] << 12) | (unsigned)A.dst[e];
            const unsigned long long tag  = (unsigned long long)(key + 1u);
            const unsigned long long pack = (tag << 24) | (unsigned long long)e;
            unsigned idx = hash_key(key);
            while (true) {
                unsigned long long cur = A.tbl[idx];
                if (cur == 0ull) {
                    unsigned long long old = atomicCAS(&A.tbl[idx], 0ull, pack);
                    if (old == 0ull) { action = 1; break; }  // claimed empty slot
                    cur = old;
                }
                if ((cur >> 24) == tag) {
                    const unsigned long long old = atomicMax(&A.tbl[idx], pack);
                    if (old < pack) {            // we are the new winner
                        action = 1;
                        sub_e = (int)(old & 0xFFFFFFull);
                    }                            // else: bigger e already added
                    break;
                }
                idx = (idx + 1u) & TBL_MASK;
            }
        }
#pragma unroll
        for (int j = 0; j < 4; ++j) {
            const int act = __shfl(action, j);
            if (!act) continue;
            const int e  = ebase + j;
            const int sj = A.src[e];            // wave-uniform scalar loads
            const int dj = A.dst[e];
            const int se = __shfl(sub_e, j);
            float c0 = A.ep[e];
            float c1 = A.ep[65536 + e];
            float c2 = A.ep[131072 + e];
            float c3 = A.ep[196608 + e];
            if (se >= 0) {                      // cancel superseded duplicate
                c0 -= A.ep[se];
                c1 -= A.ep[65536 + se];
                c2 -= A.ep[131072 + se];
                c3 -= A.ep[196608 + se];
            }
            const int base = dj * 64 + lane;
            float v = c0 * r0 * A.nproj[base];
            v = fmaf(c1 * r1, A.nproj[base + 262144], v);
            v = fmaf(c2 * r2, A.nproj[base + 524288], v);
            v = fmaf(c3 * r3, A.nproj[base + 786432], v);
            unsafeAtomicAdd(&A.out[sj * 64 + lane], v);
        }
    }
}

// ---------------------------------------------------------------------------
extern "C" void kernel_launch(void* const* d_in, const int* in_sizes, int n_in,
                              void* d_out, int out_size, void* d_ws, size_t ws_size,
                              hipStream_t stream) {
    Args A;
    A.X   = (const float*)d_in[0];
    A.Xe  = (const float*)d_in[1];
    A.src = (const int*)d_in[2];
    A.dst = (const int*)d_in[3];
    A.Wn  = (const float*)d_in[4];
    A.bn  = (const float*)d_in[5];
    A.We  = (const float*)d_in[6];
    A.be  = (const float*)d_in[7];
    A.out = (float*)d_out;
    char* ws   = (char*)d_ws;
    A.nproj    = (float*)ws;                                     // 4 MB
    A.ep       = (float*)(ws + 4u * 1024u * 1024u);              // 1 MB
    A.partials = (float*)(ws + 5u * 1024u * 1024u);              // 4 KB
    A.tbl      = (unsigned long long*)(ws + 6u * 1024u * 1024u); // 2 MB

    k_a<<<GBLK, BLK, 0, stream>>>(A);
    k_b<<<2048, BLK, 0, stream>>>(A);
}